// Round 1
// baseline (196.471 us; speedup 1.0000x reference)
//
#include <hip/hip_runtime.h>

// VQ-VAE eval forward on MI355X (gfx950).
// B=64, D=64, H=32, W=32 -> N = B*H*W = 65536 queries of dim 64; K=1024 codes.
// Outputs (concatenated float32): z_q[4194304], loss[1], indices[65536], usage[1].

#define DIMS 64
#define K_CODES 1024
#define N_QUERIES 65536
#define HW 1024              // H*W
#define TOTAL_ELEMS 4194304  // B*D*H*W

// ws layout (bytes): [0,4096) float norms[1024]; [4096,8192) int flags[1024]; [8192] float loss_acc

// ---------------- Kernel A: code norms + zero accumulators ----------------
__global__ void vq_prep(const float* __restrict__ emb, float* __restrict__ ws_norm,
                        int* __restrict__ ws_flags, float* __restrict__ ws_loss) {
    int k = blockIdx.x * 256 + threadIdx.x;  // 0..1023
    const float4* row = (const float4*)(emb + k * DIMS);
    float s = 0.f;
#pragma unroll
    for (int i = 0; i < 16; ++i) {
        float4 v = row[i];
        s += v.x * v.x + v.y * v.y + v.z * v.z + v.w * v.w;
    }
    ws_norm[k] = s;
    ws_flags[k] = 0;
    if (k == 0) *ws_loss = 0.f;
}

// ---------------- Kernel B: distances + argmin + gather + loss ----------------
// 512 blocks x 256 threads. Block owns 128 queries (2 per lane, all 4 waves share them).
// Wave w handles codes [w*256, w*256+256) in 8 tiles of 32 codes staged in LDS.
__global__ __launch_bounds__(256, 2)
void vq_main(const float* __restrict__ z_e, const float* __restrict__ emb,
             const float* __restrict__ ws_norm, int* __restrict__ ws_flags,
             float* __restrict__ ws_loss, float* __restrict__ out) {
    __shared__ float4 ldsT[4][32 * 16];  // per-wave 32 codes x 64 dims (32 KB)
    __shared__ float  ldsN[4][32];
    __shared__ float  rD[4][128];
    __shared__ int    rI[4][128];
    __shared__ int    fIdx[128];
    __shared__ float  wsum[4];

    const int tid  = threadIdx.x;
    const int lane = tid & 63;
    const int wid  = tid >> 6;
    const int qbase = blockIdx.x * 128;

    // Load this lane's two queries into registers.
    // flat[n][d] = z_e[b*D*HW + d*HW + (n & (HW-1))], b = n >> 10. b uniform per block.
    const int n0  = qbase + lane;
    const int b   = n0 >> 10;
    const int hw0 = n0 & (HW - 1);
    const int hw1 = (n0 + 64) & (HW - 1);
    const float* zb = z_e + b * (DIMS * HW);
    float x0[DIMS], x1[DIMS];
#pragma unroll
    for (int d = 0; d < DIMS; ++d) {
        x0[d] = zb[d * HW + hw0];   // lanes consecutive -> coalesced
        x1[d] = zb[d * HW + hw1];
    }

    const int wk0 = wid * 256;  // this wave's code range base
    float best0 = 3.4e38f, best1 = 3.4e38f;
    int   bi0 = 0, bi1 = 0;

    for (int t = 0; t < 8; ++t) {
        __syncthreads();  // previous tile fully consumed by all waves
        // Stage 32 codes x 64 dims (512 float4) for this wave; coalesced.
        const float4* gsrc = (const float4*)(emb + (wk0 + t * 32) * DIMS);
#pragma unroll
        for (int i = 0; i < 8; ++i)
            ldsT[wid][i * 64 + lane] = gsrc[i * 64 + lane];
        if (lane < 32) ldsN[wid][lane] = ws_norm[wk0 + t * 32 + lane];
        __syncthreads();

        for (int jj = 0; jj < 32; ++jj) {
            const float4* e = &ldsT[wid][jj * 16];  // wave-uniform address -> broadcast
            float4 a0 = {0.f, 0.f, 0.f, 0.f};
            float4 a1 = {0.f, 0.f, 0.f, 0.f};
#pragma unroll
            for (int c = 0; c < 16; ++c) {
                float4 ev = e[c];
                a0.x += x0[4 * c + 0] * ev.x;
                a0.y += x0[4 * c + 1] * ev.y;
                a0.z += x0[4 * c + 2] * ev.z;
                a0.w += x0[4 * c + 3] * ev.w;
                a1.x += x1[4 * c + 0] * ev.x;
                a1.y += x1[4 * c + 1] * ev.y;
                a1.z += x1[4 * c + 2] * ev.z;
                a1.w += x1[4 * c + 3] * ev.w;
            }
            float dot0 = (a0.x + a0.y) + (a0.z + a0.w);
            float dot1 = (a1.x + a1.y) + (a1.z + a1.w);
            float nrm  = ldsN[wid][jj];
            float dist0 = fmaf(-2.f, dot0, nrm);  // ||x||^2 dropped: constant per query
            float dist1 = fmaf(-2.f, dot1, nrm);
            int j = wk0 + t * 32 + jj;
            if (dist0 < best0) { best0 = dist0; bi0 = j; }  // strict < = first-min
            if (dist1 < best1) { best1 = dist1; bi1 = j; }
        }
    }

    // Cross-wave argmin reduce (waves cover ascending code ranges).
    rD[wid][lane]      = best0; rI[wid][lane]      = bi0;
    rD[wid][lane + 64] = best1; rI[wid][lane + 64] = bi1;
    __syncthreads();
    if (tid < 128) {
        float dbest = rD[0][tid];
        int   ibest = rI[0][tid];
#pragma unroll
        for (int w = 1; w < 4; ++w) {
            float dw = rD[w][tid];
            int   iw = rI[w][tid];
            if (dw < dbest || (dw == dbest && iw < ibest)) { dbest = dw; ibest = iw; }
        }
        fIdx[tid] = ibest;
        out[TOTAL_ELEMS + 1 + qbase + tid] = (float)ibest;  // indices output
        ws_flags[ibest] = 1;                                // usage flag (benign race)
    }
    __syncthreads();

    // Gather z_q, write coalesced, accumulate mse partial.
    const int q  = tid & 127;
    const int dh = tid >> 7;           // 0/1: even/odd dims
    const int n  = qbase + q;
    const int bb = n >> 10;
    const int hw = n & (HW - 1);
    const int myIdx = fIdx[q];
    const float* erow = emb + myIdx * DIMS;
    float lsum = 0.f;
#pragma unroll
    for (int it = 0; it < 32; ++it) {
        int d = it * 2 + dh;
        float v = erow[d];                        // random row, L2-resident
        int   o = bb * (DIMS * HW) + d * HW + hw; // consecutive q -> coalesced
        float ze = z_e[o];
        out[o] = v;
        float df = ze - v;
        lsum = fmaf(df, df, lsum);
    }
    // block-level mse reduce
#pragma unroll
    for (int off = 32; off > 0; off >>= 1) lsum += __shfl_down(lsum, off, 64);
    if (lane == 0) wsum[wid] = lsum;
    __syncthreads();
    if (tid == 0) atomicAdd(ws_loss, wsum[0] + wsum[1] + wsum[2] + wsum[3]);
}

// ---------------- Kernel C: finalize loss + usage ----------------
__global__ void vq_final(const int* __restrict__ flags, const float* __restrict__ loss,
                         float* __restrict__ out) {
    __shared__ int cnt[256];
    int tid = threadIdx.x;
    int c = flags[tid] + flags[tid + 256] + flags[tid + 512] + flags[tid + 768];
    cnt[tid] = c;
    __syncthreads();
    for (int s = 128; s > 0; s >>= 1) {
        if (tid < s) cnt[tid] += cnt[tid + s];
        __syncthreads();
    }
    if (tid == 0) {
        out[TOTAL_ELEMS] = *loss / (float)TOTAL_ELEMS;
        out[TOTAL_ELEMS + 1 + N_QUERIES] = (float)cnt[0] / (float)K_CODES;
    }
}

extern "C" void kernel_launch(void* const* d_in, const int* in_sizes, int n_in,
                              void* d_out, int out_size, void* d_ws, size_t ws_size,
                              hipStream_t stream) {
    const float* z_e = (const float*)d_in[0];
    const float* emb = (const float*)d_in[1];
    float* out = (float*)d_out;
    float* ws_norm  = (float*)d_ws;
    int*   ws_flags = (int*)((char*)d_ws + 4096);
    float* ws_loss  = (float*)((char*)d_ws + 8192);

    vq_prep<<<4, 256, 0, stream>>>(emb, ws_norm, ws_flags, ws_loss);
    vq_main<<<512, 256, 0, stream>>>(z_e, emb, ws_norm, ws_flags, ws_loss, out);
    vq_final<<<1, 256, 0, stream>>>(ws_flags, ws_loss, out);
}

// Round 2
// 135.801 us; speedup vs baseline: 1.4468x; 1.4468x over previous
//
#include <hip/hip_runtime.h>

// VQ-VAE eval forward, MFMA bf16x3-split path (fp32-faithful distances).
// B=64, D=64, H=32, W=32 -> N=65536 queries dim 64; K=1024 codes.
// dist(q,c) = ||e_c||^2 - 2 <x_q, e_c>  (||x||^2 dropped: per-query constant,
// fp32 add of a constant is monotonic -> argmin preserved incl. tie order).
// <x,e> via 6 bf16 MFMA products: x=xh+xm+xl exactly (8+8+8 bits), keep
// hh,hm,mh,mm,hl,lh -> error ~2^-27*scale, below fp32 reorder noise.

#define DIMS 64
#define K_CODES 1024
#define N_QUERIES 65536
#define HW 1024
#define TOTAL_ELEMS 4194304
#define PLANE 4096  // shorts per plane in a code-tile buffer: 8 octets * 64 codes * 8

typedef __attribute__((ext_vector_type(8))) short v8s;   // 8 bf16 = 4 VGPR (A/B frag)
typedef __attribute__((ext_vector_type(4))) float f32x4; // C/D frag

__device__ inline unsigned short f2bf(float x) {
    union { float f; unsigned u; } v; v.f = x;
    unsigned r = v.u + 0x7fff + ((v.u >> 16) & 1);  // RNE
    return (unsigned short)(r >> 16);
}
__device__ inline float bf2f(unsigned short h) {
    union { unsigned u; float f; } v; v.u = ((unsigned)h) << 16; return v.f;
}

// ---------------- Kernel A: code norms + zero accumulators ----------------
__global__ void vq_prep(const float* __restrict__ emb, float* __restrict__ ws_norm,
                        int* __restrict__ ws_flags, float* __restrict__ ws_loss) {
    int k = blockIdx.x * 256 + threadIdx.x;  // 0..1023
    const float4* row = (const float4*)(emb + k * DIMS);
    float s = 0.f;
#pragma unroll
    for (int i = 0; i < 16; ++i) {
        float4 v = row[i];
        s += v.x * v.x + v.y * v.y + v.z * v.z + v.w * v.w;
    }
    ws_norm[k] = s;
    ws_flags[k] = 0;
    if (k == 0) *ws_loss = 0.f;
}

#define MFMA16(A_, B_, C_) __builtin_amdgcn_mfma_f32_16x16x32_bf16(A_, B_, C_, 0, 0, 0)

// ---------------- Kernel B: MFMA distances + argmin + gather + loss ----------------
// 512 blocks x 256 threads (4 waves). Block = 128 queries; wave = 32 queries
// (2 row-tiles of 16), each wave scans ALL 1024 codes in 16 tiles of 64.
__global__ __launch_bounds__(256, 2)
void vq_main(const float* __restrict__ z_e, const float* __restrict__ emb,
             const float* __restrict__ ws_norm, int* __restrict__ ws_flags,
             float* __restrict__ ws_loss, float* __restrict__ out) {
    // Double-buffered code tile, frag-ready: [buf][plane p][octet o][code][8 bf16]
    __shared__ unsigned short ldsB[2][3 * PLANE];  // 48 KB
    __shared__ int   fIdx[128];
    __shared__ float wsum[4];

    const int tid  = threadIdx.x;
    const int lane = tid & 63;
    const int wid  = tid >> 6;
    const int qbase = blockIdx.x * 128;
    const int b    = qbase >> 10;          // batch index (uniform per block)
    const int hwb  = qbase & (HW - 1);

    const int col  = lane & 15;  // m (A) / n (B) within 16-tile
    const int qd   = lane >> 4;  // quad -> k-octet selector

    // ---- Build A fragments from global (coalesced), split into 3 bf16 planes ----
    // A[m=col][k=qd*8+j]; dims d = kc*32 + qd*8 + j. afr[rt][kc][plane]
    v8s afr[2][2][3];
    {
        const float* zb = z_e + b * (DIMS * HW);
#pragma unroll
        for (int rt = 0; rt < 2; ++rt) {
            int hwq = hwb + wid * 32 + rt * 16 + col;
#pragma unroll
            for (int kc = 0; kc < 2; ++kc) {
                int dbase = kc * 32 + qd * 8;
#pragma unroll
                for (int j = 0; j < 8; ++j) {
                    float x = zb[(dbase + j) * HW + hwq];
                    unsigned short h = f2bf(x);  float r1 = x - bf2f(h);
                    unsigned short m = f2bf(r1); float r2 = r1 - bf2f(m);
                    afr[rt][kc][0][j] = (short)h;
                    afr[rt][kc][1][j] = (short)m;
                    afr[rt][kc][2][j] = (short)f2bf(r2);
                }
            }
        }
    }

    float bestv[2][4];
    int   besti[2][4];
#pragma unroll
    for (int rt = 0; rt < 2; ++rt)
#pragma unroll
        for (int r = 0; r < 4; ++r) { bestv[rt][r] = 3.4e38f; besti[rt][r] = 0; }

    float4 regs[4];  // staging pipeline registers (16 fp32 = one 64-code tile / 256 thr)

    // Stage tile t's 64x64 fp32 into regs (fully coalesced: tile is contiguous).
    auto stage_loads = [&](int t) {
        const float4* src = (const float4*)(emb + t * 64 * DIMS);
#pragma unroll
        for (int i = 0; i < 4; ++i) regs[i] = src[tid + 256 * i];
    };
    // Split + scatter into frag-ready LDS layout (8B ds_writes).
    auto stage_write = [&](int bb) {
        unsigned short* dst = &ldsB[bb][0];
#pragma unroll
        for (int i = 0; i < 4; ++i) {
            int e    = (tid + 256 * i) * 4;  // flat element in tile
            int code = e >> 6;
            int d    = e & 63;               // 4-aligned
            int o    = d >> 3;
            int sub  = d & 7;                // 0 or 4
            float xs[4] = {regs[i].x, regs[i].y, regs[i].z, regs[i].w};
            unsigned short h[4], mm_[4], l[4];
#pragma unroll
            for (int q = 0; q < 4; ++q) {
                float x = xs[q];
                unsigned short hh = f2bf(x);  float r1 = x - bf2f(hh);
                unsigned short mh = f2bf(r1); float r2 = r1 - bf2f(mh);
                h[q] = hh; mm_[q] = mh; l[q] = f2bf(r2);
            }
            int base = (o * 64 + code) * 8 + sub;  // shorts, 8B-aligned
            uint2 uh, um, ul;
            uh.x = (unsigned)h[0]   | ((unsigned)h[1] << 16);
            uh.y = (unsigned)h[2]   | ((unsigned)h[3] << 16);
            um.x = (unsigned)mm_[0] | ((unsigned)mm_[1] << 16);
            um.y = (unsigned)mm_[2] | ((unsigned)mm_[3] << 16);
            ul.x = (unsigned)l[0]   | ((unsigned)l[1] << 16);
            ul.y = (unsigned)l[2]   | ((unsigned)l[3] << 16);
            *(uint2*)(dst + base)             = uh;
            *(uint2*)(dst + PLANE + base)     = um;
            *(uint2*)(dst + 2 * PLANE + base) = ul;
        }
    };

    stage_loads(0);
    stage_write(0);
    __syncthreads();

    for (int t = 0; t < 16; ++t) {
        const int cur = t & 1;
        if (t < 15) stage_loads(t + 1);
        const unsigned short* bufc = &ldsB[cur][0];
#pragma unroll
        for (int cs = 0; cs < 4; ++cs) {
            float nrm = ws_norm[t * 64 + cs * 16 + col];
            // B-frags: B[n=col][k=qd*8+j], octet = kc*4+qd, for 3 planes.
            v8s bfr[2][3];
#pragma unroll
            for (int kc = 0; kc < 2; ++kc)
#pragma unroll
                for (int p = 0; p < 3; ++p)
                    bfr[kc][p] = *(const v8s*)(bufc + p * PLANE +
                                 (((kc * 4 + qd) * 64) + cs * 16 + col) * 8);
            f32x4 acc0 = {0.f, 0.f, 0.f, 0.f};
            f32x4 acc1 = {0.f, 0.f, 0.f, 0.f};
#pragma unroll
            for (int kc = 0; kc < 2; ++kc) {
                acc0 = MFMA16(afr[0][kc][0], bfr[kc][0], acc0);  // hh
                acc1 = MFMA16(afr[1][kc][0], bfr[kc][0], acc1);
                acc0 = MFMA16(afr[0][kc][0], bfr[kc][1], acc0);  // hm
                acc1 = MFMA16(afr[1][kc][0], bfr[kc][1], acc1);
                acc0 = MFMA16(afr[0][kc][1], bfr[kc][0], acc0);  // mh
                acc1 = MFMA16(afr[1][kc][1], bfr[kc][0], acc1);
                acc0 = MFMA16(afr[0][kc][1], bfr[kc][1], acc0);  // mm
                acc1 = MFMA16(afr[1][kc][1], bfr[kc][1], acc1);
                acc0 = MFMA16(afr[0][kc][0], bfr[kc][2], acc0);  // hl
                acc1 = MFMA16(afr[1][kc][0], bfr[kc][2], acc1);
                acc0 = MFMA16(afr[0][kc][2], bfr[kc][0], acc0);  // lh
                acc1 = MFMA16(afr[1][kc][2], bfr[kc][0], acc1);
            }
            int cbase = t * 64 + cs * 16 + col;
#pragma unroll
            for (int r = 0; r < 4; ++r) {
                float d0 = fmaf(-2.f, acc0[r], nrm);
                if (d0 < bestv[0][r]) { bestv[0][r] = d0; besti[0][r] = cbase; }
                float d1 = fmaf(-2.f, acc1[r], nrm);
                if (d1 < bestv[1][r]) { bestv[1][r] = d1; besti[1][r] = cbase; }
            }
        }
        if (t < 15) stage_write(1 - cur);  // other buffer: safe while peers finish cur
        __syncthreads();
    }

    // ---- Final argmin across the 16 columns held by this quad's lanes ----
    // C/D: row = qd*4 + r, col = lane&15. Lanes of a quad share rows, span cols.
#pragma unroll
    for (int rt = 0; rt < 2; ++rt)
#pragma unroll
    for (int r = 0; r < 4; ++r) {
        float v = bestv[rt][r];
        int   idx = besti[rt][r];
#pragma unroll
        for (int m = 8; m >= 1; m >>= 1) {
            float ov = __shfl_xor(v, m, 64);
            int   oi = __shfl_xor(idx, m, 64);
            if (ov < v || (ov == v && oi < idx)) { v = ov; idx = oi; }
        }
        if (col == 0) {
            int q = wid * 32 + rt * 16 + qd * 4 + r;  // within block
            fIdx[q] = idx;
            out[TOTAL_ELEMS + 1 + qbase + q] = (float)idx;
            ws_flags[idx] = 1;  // benign race
        }
    }
    __syncthreads();

    // ---- Gather z_q, write coalesced, accumulate mse partial ----
    const int q  = tid & 127;
    const int dh = tid >> 7;  // even/odd dims
    const int n  = qbase + q;
    const int bb = n >> 10;
    const int hw = n & (HW - 1);
    const int myIdx = fIdx[q];
    const float* erow = emb + myIdx * DIMS;
    float lsum = 0.f;
#pragma unroll
    for (int it = 0; it < 32; ++it) {
        int d = it * 2 + dh;
        float v = erow[d];                         // random row, L2/L3-resident
        int   o = bb * (DIMS * HW) + d * HW + hw;  // consecutive q -> coalesced
        float ze = z_e[o];
        out[o] = v;
        float df = ze - v;
        lsum = fmaf(df, df, lsum);
    }
#pragma unroll
    for (int off = 32; off > 0; off >>= 1) lsum += __shfl_down(lsum, off, 64);
    if (lane == 0) wsum[wid] = lsum;
    __syncthreads();
    if (tid == 0) atomicAdd(ws_loss, wsum[0] + wsum[1] + wsum[2] + wsum[3]);
}

// ---------------- Kernel C: finalize loss + usage ----------------
__global__ void vq_final(const int* __restrict__ flags, const float* __restrict__ loss,
                         float* __restrict__ out) {
    __shared__ int cnt[256];
    int tid = threadIdx.x;
    int c = flags[tid] + flags[tid + 256] + flags[tid + 512] + flags[tid + 768];
    cnt[tid] = c;
    __syncthreads();
    for (int s = 128; s > 0; s >>= 1) {
        if (tid < s) cnt[tid] += cnt[tid + s];
        __syncthreads();
    }
    if (tid == 0) {
        out[TOTAL_ELEMS] = *loss / (float)TOTAL_ELEMS;
        out[TOTAL_ELEMS + 1 + N_QUERIES] = (float)cnt[0] / (float)K_CODES;
    }
}

extern "C" void kernel_launch(void* const* d_in, const int* in_sizes, int n_in,
                              void* d_out, int out_size, void* d_ws, size_t ws_size,
                              hipStream_t stream) {
    const float* z_e = (const float*)d_in[0];
    const float* emb = (const float*)d_in[1];
    float* out = (float*)d_out;
    float* ws_norm  = (float*)d_ws;
    int*   ws_flags = (int*)((char*)d_ws + 4096);
    float* ws_loss  = (float*)((char*)d_ws + 8192);

    vq_prep<<<4, 256, 0, stream>>>(emb, ws_norm, ws_flags, ws_loss);
    vq_main<<<512, 256, 0, stream>>>(z_e, emb, ws_norm, ws_flags, ws_loss, out);
    vq_final<<<1, 256, 0, stream>>>(ws_flags, ws_loss, out);
}